// Round 9
// baseline (213.878 us; speedup 1.0000x reference)
//
#include <hip/hip_runtime.h>
#include <cstdint>
#include <cstddef>

#define DI __device__ __forceinline__

typedef __attribute__((ext_vector_type(8))) short bf16x8;   // 8 bf16 in 4 VGPRs
typedef __attribute__((ext_vector_type(4))) float f32x4;
using u16 = unsigned short;

struct Sel { int i0, i1; float g0, g1; };

DI u16 f2bf(float f) {
  union { float f; unsigned u; } c; c.f = f;
  unsigned u = c.u;
  unsigned r = (u + 0x7fffu + ((u >> 16) & 1u)) >> 16;   // RNE
  return (u16)r;
}

DI float softplus_f(float z) {
  return (z > 0.f) ? (z + log1pf(expf(-z))) : log1pf(expf(z));
}

DI void async16(const void* g, void* l) {
  __builtin_amdgcn_global_load_lds(
      (const __attribute__((address_space(1))) unsigned int*)g,
      (__attribute__((address_space(3))) unsigned int*)l, 16, 0, 0);
}

#define MFMA_BF16(a, b, c) \
  c = __builtin_amdgcn_mfma_f32_16x16x32_bf16(a, b, c, 0, 0, 0)

// ---------------------------------------------------------------------------
// cvt_gb: gn,gw [1024i][64e] f32 -> gbT [128][1024] bf16 (rows 0-63 = gn^T,
// rows 64-127 = gw^T), plain layout (gate reads it straight from L2).
// 16 blocks x 256 thr.
// ---------------------------------------------------------------------------
__global__ __launch_bounds__(256) void cvt_gb(
    const float* __restrict__ gw, const float* __restrict__ gn,
    u16* __restrict__ gbT) {
  __shared__ float tile[64][65];
  const int tid = threadIdx.x;
  const int i0 = blockIdx.x * 64;
  for (int pass = 0; pass < 2; ++pass) {
    const float* src = pass ? gw : gn;
    if (pass) __syncthreads();
#pragma unroll
    for (int j = 0; j < 16; ++j) {
      int lin = j * 256 + tid;
      int r = lin >> 6, c = lin & 63;
      tile[r][c] = src[(size_t)(i0 + r) * 64 + c];
    }
    __syncthreads();
#pragma unroll
    for (int j = 0; j < 16; ++j) {
      int lin = j * 256 + tid;
      int e = lin >> 6, r2 = lin & 63;
      gbT[(size_t)(pass * 64 + e) * 1024 + i0 + r2] = f2bf(tile[r2][e]);
    }
  }
}

// ---------------------------------------------------------------------------
// gate_fused: 1024 blocks x 256 thr, 16 tokens each. LDS = 32 KB (4 blk/CU).
// Phase A: stream x f32 -> bf16 -> xb (global) + swizzled smX[16][1024].
// Phase B: logits[16][128] = smX @ gbT^T via MFMA; B-fragments read DIRECTLY
// from global (gbT is 256 KB, L2-resident, reused by all blocks) -- no LDS
// staging, no per-iter barriers. One barrier total.
// ---------------------------------------------------------------------------
__global__ __launch_bounds__(256) void gate_fused(
    const float* __restrict__ x, const u16* __restrict__ gbT,
    u16* __restrict__ xb, float* __restrict__ part) {
  __shared__ u16 smX[16 * 1024];        // 32 KB
  __shared__ float red[4][64];
  const int tid = threadIdx.x;
  const int wave = tid >> 6, lane = tid & 63;
  const int tok0 = blockIdx.x * 16;

  // ---- Phase A: stream + convert (thread owns 4 cols x 16 rows)
  {
    const int c0 = tid * 4;
    const int g = c0 >> 3, sub = c0 & 7;
#pragma unroll 4
    for (int r = 0; r < 16; ++r) {
      float4 v = *(const float4*)&x[(size_t)(tok0 + r) * 1024 + c0];
      ushort4 o; o.x = f2bf(v.x); o.y = f2bf(v.y); o.z = f2bf(v.z); o.w = f2bf(v.w);
      *(ushort4*)&xb[(size_t)(tok0 + r) * 1024 + c0] = o;
      const int sc = (((g ^ (r & 7)) << 3) | sub);
      *(ushort4*)&smX[r * 1024 + sc] = o;
    }
  }
  asm volatile("s_waitcnt lgkmcnt(0)" ::: "memory");
  __builtin_amdgcn_s_barrier();          // smX ready (xb stores may fly on)

  const int fr = lane & 15;
  const int q = lane >> 4;
  const int f7 = fr & 7;
  const int arow = fr * 1024;
  // B-frag global bases: expert row = wave*32 + f*16 + fr, k-offset q*8
  const u16* gB0 = gbT + (size_t)(wave * 32 + fr) * 1024 + q * 8;
  const u16* gB1 = gB0 + 16 * 1024;

  f32x4 acc[2] = {};   // f = 0,1 -> experts wave*32 + f*16 + fr

#pragma unroll 4
  for (int t = 0; t < 16; ++t) {
    bf16x8 a0 = *(const bf16x8*)(smX + arow + (((t * 8 + q) ^ f7) << 3));
    bf16x8 a1 = *(const bf16x8*)(smX + arow + (((t * 8 + 4 + q) ^ f7) << 3));
    bf16x8 b00 = *(const bf16x8*)(gB0 + t * 64);
    bf16x8 b01 = *(const bf16x8*)(gB0 + t * 64 + 32);
    bf16x8 b10 = *(const bf16x8*)(gB1 + t * 64);
    bf16x8 b11 = *(const bf16x8*)(gB1 + t * 64 + 32);
    MFMA_BF16(a0, b00, acc[0]);
    MFMA_BF16(a1, b01, acc[0]);
    MFMA_BF16(a0, b10, acc[1]);
    MFMA_BF16(a1, b11, acc[1]);
  }

  // C layout: expert = wave*32 + f*16 + fr ; token = q*4 + reg.
#pragma unroll
  for (int f = 0; f < 2; ++f) {
    float s;
    if (wave < 2)
      s = softplus_f(acc[f][0]) + softplus_f(acc[f][1]) +
          softplus_f(acc[f][2]) + softplus_f(acc[f][3]);
    else
      s = (acc[f][0] + acc[f][1]) + (acc[f][2] + acc[f][3]);
    s += __shfl_xor(s, 16);
    s += __shfl_xor(s, 32);
    if (q == 0)
      red[wave][(f << 4) | fr] = s;      // stash via regs; direct store below
  }
  if (q == 0) {
#pragma unroll
    for (int f = 0; f < 2; ++f)
      part[(size_t)blockIdx.x * 128 + wave * 32 + f * 16 + fr] =
          red[wave][(f << 4) | fr];
  }
}

// ---------------------------------------------------------------------------
// reduce_parts: [1024][128] -> [32][128]. 32 blocks x 256 thr.
// ---------------------------------------------------------------------------
__global__ __launch_bounds__(256) void reduce_parts(
    const float* __restrict__ part, float* __restrict__ p2) {
  __shared__ float rs[2][128];
  const int bb = blockIdx.x, tid = threadIdx.x;
  const int idx = tid & 127, sub = tid >> 7;
  const float* src = part + (size_t)(bb * 32 + sub * 16) * 128 + idx;
  float s0 = 0.f, s1 = 0.f, s2 = 0.f, s3 = 0.f;
#pragma unroll
  for (int j = 0; j < 16; j += 4) {
    s0 += src[(j + 0) * 128];
    s1 += src[(j + 1) * 128];
    s2 += src[(j + 2) * 128];
    s3 += src[(j + 3) * 128];
  }
  rs[sub][idx] = (s0 + s1) + (s2 + s3);
  __syncthreads();
  if (sub == 0) p2[(size_t)bb * 128 + idx] = rs[0][idx] + rs[1][idx];
}

// ---------------------------------------------------------------------------
// select: reduce 32 partials, mean logits, top-2, gates, combined biases.
// ---------------------------------------------------------------------------
__global__ __launch_bounds__(256) void select_kernel(
    const float* __restrict__ p2, const float* __restrict__ noise,
    const float* __restrict__ bi, const float* __restrict__ bo,
    Sel* __restrict__ sel_out, float* __restrict__ bi_comb,
    float* __restrict__ bo_comb) {
  __shared__ float sums[128];
  __shared__ float ml[64];
  __shared__ Sel sl;
  const int tid = threadIdx.x;
  if (tid < 128) {
    float s0 = 0.f, s1 = 0.f, s2 = 0.f, s3 = 0.f;
#pragma unroll
    for (int b = 0; b < 32; b += 4) {
      s0 += p2[(b + 0) * 128 + tid];
      s1 += p2[(b + 1) * 128 + tid];
      s2 += p2[(b + 2) * 128 + tid];
      s3 += p2[(b + 3) * 128 + tid];
    }
    sums[tid] = (s0 + s1) + (s2 + s3);
  }
  __syncthreads();
  if (tid < 64)
    ml[tid] = (sums[64 + tid] + sums[tid] * noise[tid]) * (1.f / 16384.f);
  __syncthreads();
  if (tid == 0) {
    int i0 = 0; float v0 = ml[0];
    for (int e2 = 1; e2 < 64; ++e2) if (ml[e2] > v0) { v0 = ml[e2]; i0 = e2; }
    int i1 = (i0 == 0) ? 1 : 0; float v1 = ml[i1];
    for (int e2 = 0; e2 < 64; ++e2)
      if (e2 != i0 && ml[e2] > v1) { v1 = ml[e2]; i1 = e2; }
    float e1 = expf(v1 - v0);                 // softmax over [v0, v1]
    float inv = 1.f / (1.f + e1);
    Sel s; s.i0 = i0; s.i1 = i1; s.g0 = inv; s.g1 = e1 * inv;
    sl = s; *sel_out = s;
  }
  __syncthreads();
  Sel s = sl;
  for (int n = tid; n < 2048; n += 256) {
    int ei = (n < 1024) ? s.i0 : s.i1;
    bi_comb[n] = bi[ei * 1024 + (n & 1023)];
  }
  for (int o = tid; o < 1024; o += 256)
    bo_comb[o] = s.g0 * bo[s.i0 * 1024 + o] + s.g1 * bo[s.i1 * 1024 + o];
}

// ---------------------------------------------------------------------------
// Transpose + bf16-convert selected expert weights. (unchanged)
// ---------------------------------------------------------------------------
__global__ __launch_bounds__(256) void prep_weights(
    const float* __restrict__ Wi, const float* __restrict__ Wo,
    const Sel* __restrict__ selp, u16* __restrict__ WiT, u16* __restrict__ WoT) {
  __shared__ float tile[64][65];
  Sel s = *selp;
  const int bid = blockIdx.x;
  const float* src; float scale; u16* dst; int dld, dr0, dc0;
  if (bid < 512) {
    int tn = bid >> 4, ti = bid & 15;           // 32 n-tiles x 16 i-tiles
    int n0 = tn * 64, i0 = ti * 64;
    int k = n0 >> 10, h0 = n0 & 1023;
    int e = k ? s.i1 : s.i0;
    src = Wi + (size_t)e * 1024 * 1024 + (size_t)i0 * 1024 + h0; // [r=i][c=h]
    scale = 1.f; dst = WiT; dld = 1024; dr0 = n0; dc0 = i0;
  } else {
    int b2 = bid - 512;
    int ro = b2 >> 5, ck = b2 & 31;             // 16 o-tiles x 32 kc-tiles
    int o0 = ro * 64, kc0 = ck * 64;
    int k = kc0 >> 10, h0 = kc0 & 1023;
    int e = k ? s.i1 : s.i0;
    scale = k ? s.g1 : s.g0;
    src = Wo + (size_t)e * 1024 * 1024 + (size_t)h0 * 1024 + o0; // [r=hh][c=o]
    dst = WoT; dld = 2048; dr0 = o0; dc0 = kc0;
  }
  const int tid = threadIdx.x;
#pragma unroll
  for (int j = 0; j < 4; ++j) {
    int lin = j * 256 + tid;
    int r = lin >> 4, c4 = (lin & 15) * 4;
    float4 v = *(const float4*)&src[(size_t)r * 1024 + c4];
    tile[r][c4] = v.x; tile[r][c4 + 1] = v.y; tile[r][c4 + 2] = v.z; tile[r][c4 + 3] = v.w;
  }
  __syncthreads();
#pragma unroll
  for (int j = 0; j < 4; ++j) {
    int lin = j * 256 + tid;
    int r2 = lin >> 4, c2 = (lin & 15) * 4;     // r2: out row, c2: out col
    ushort4 o;
    o.x = f2bf(scale * tile[c2][r2]);
    o.y = f2bf(scale * tile[c2 + 1][r2]);
    o.z = f2bf(scale * tile[c2 + 2][r2]);
    o.w = f2bf(scale * tile[c2 + 3][r2]);
    *(ushort4*)&dst[(size_t)(dr0 + r2) * dld + dc0 + c2] = o;
  }
}

// ---------------------------------------------------------------------------
// 256x256 8-phase bf16 GEMM (r8 version: LDS-transpose epilogue for bf16 out).
// ---------------------------------------------------------------------------
template <int RELU, typename OUTT>
__global__ __launch_bounds__(512) void gemm256(
    const u16* __restrict__ A, const u16* __restrict__ Bt,
    const float* __restrict__ bias, OUTT* __restrict__ C,
    int N, int K, int nN) {
  __shared__ u16 lds[65536];            // [0,32K): A dbuf | [32K,64K): B dbuf
  const int tid = threadIdx.x;
  const int wave = tid >> 6, lane = tid & 63;

  // XCD-aware bijective remap (gridDim.x % 8 == 0)
  const int cpx = gridDim.x >> 3;
  const int wg = (blockIdx.x & 7) * cpx + (blockIdx.x >> 3);
  const int m0 = (wg / nN) * 256, n0 = (wg % nN) * 256;
  const int wm = wave >> 2, wn = wave & 3;

  f32x4 acc[8][4] = {};

  const int srow = wave * 8 + (lane >> 3);
  const int gcol = (((lane & 7) ^ ((lane >> 3) & 7)) << 3);
  const u16* gA = A + (size_t)(m0 + srow) * K + gcol;
  const u16* gB = Bt + (size_t)(n0 + srow) * K + gcol;
  const int ldsOff = wave * 512;

  const int NT = K >> 6;

  auto stageA = [&](int t) {
    const u16* a = gA + t * 64;
    u16* la = lds + (t & 1) * 16384 + ldsOff;
#pragma unroll
    for (int j = 0; j < 4; ++j) async16(a + (size_t)j * 64 * K, la + j * 4096);
  };
  auto stageB = [&](int t) {
    const u16* b = gB + t * 64;
    u16* lb = lds + 32768 + (t & 1) * 16384 + ldsOff;
#pragma unroll
    for (int j = 0; j < 4; ++j) async16(b + (size_t)j * 64 * K, lb + j * 4096);
  };

  stageB(0); stageA(0);
  stageB(1); stageA(1);
  asm volatile("s_waitcnt vmcnt(8)\ns_barrier" ::: "memory");

  const int fr = lane & 15;
  const int cx = (lane & 7) << 3;
  const int cb0 = (((lane >> 4) << 3)) ^ cx;        // kk=0 col (elems)
  const int cb1 = (32 | ((lane >> 4) << 3)) ^ cx;   // kk=1 col (elems)

  bf16x8 af[4][2], b0r[2][2], b1r[2][2];

  for (int t = 0; t < NT; ++t) {
    const u16* Ab = lds + (t & 1) * 16384;
    const u16* Bb = lds + 32768 + (t & 1) * 16384;

    // ============ P0: read A[mq=0], B[nq=0]; mfma (0,0)
#pragma unroll
    for (int m = 0; m < 4; ++m) {
      const int rA = (wm * 128 + m * 16 + fr) * 64;
      af[m][0] = *(const bf16x8*)(Ab + rA + cb0);
      af[m][1] = *(const bf16x8*)(Ab + rA + cb1);
    }
#pragma unroll
    for (int n = 0; n < 2; ++n) {
      const int rB = (wn * 64 + n * 16 + fr) * 64;
      b0r[n][0] = *(const bf16x8*)(Bb + rB + cb0);
      b0r[n][1] = *(const bf16x8*)(Bb + rB + cb1);
    }
    __builtin_amdgcn_s_barrier();
    asm volatile("s_waitcnt lgkmcnt(0)" ::: "memory");
    __builtin_amdgcn_sched_barrier(0);
    __builtin_amdgcn_s_setprio(1);
#pragma unroll
    for (int m = 0; m < 4; ++m)
#pragma unroll
      for (int n = 0; n < 2; ++n) {
        MFMA_BF16(af[m][0], b0r[n][0], acc[m][n]);
        MFMA_BF16(af[m][1], b0r[n][1], acc[m][n]);
      }
    __builtin_amdgcn_s_setprio(0);
    __builtin_amdgcn_s_barrier();

    // ============ P1: read B[nq=1]; mfma (0,1)
#pragma unroll
    for (int n = 0; n < 2; ++n) {
      const int rB = (wn * 64 + 32 + n * 16 + fr) * 64;
      b1r[n][0] = *(const bf16x8*)(Bb + rB + cb0);
      b1r[n][1] = *(const bf16x8*)(Bb + rB + cb1);
    }
    __builtin_amdgcn_s_barrier();
    asm volatile("s_waitcnt lgkmcnt(0)" ::: "memory");
    __builtin_amdgcn_sched_barrier(0);
    __builtin_amdgcn_s_setprio(1);
#pragma unroll
    for (int m = 0; m < 4; ++m)
#pragma unroll
      for (int n = 0; n < 2; ++n) {
        MFMA_BF16(af[m][0], b1r[n][0], acc[m][2 + n]);
        MFMA_BF16(af[m][1], b1r[n][1], acc[m][2 + n]);
      }
    __builtin_amdgcn_s_setprio(0);
    __builtin_amdgcn_s_barrier();

    // ============ P2: read A[mq=1]; stage B(t+2); mfma (1,1)
#pragma unroll
    for (int m = 0; m < 4; ++m) {
      const int rA = (wm * 128 + 64 + m * 16 + fr) * 64;
      af[m][0] = *(const bf16x8*)(Ab + rA + cb0);
      af[m][1] = *(const bf16x8*)(Ab + rA + cb1);
    }
    if (t + 2 < NT) stageB(t + 2);
    __builtin_amdgcn_s_barrier();
    asm volatile("s_waitcnt lgkmcnt(0)" ::: "memory");
    __builtin_amdgcn_sched_barrier(0);
    __builtin_amdgcn_s_setprio(1);
#pragma unroll
    for (int m = 0; m < 4; ++m)
#pragma unroll
      for (int n = 0; n < 2; ++n) {
        MFMA_BF16(af[m][0], b1r[n][0], acc[4 + m][2 + n]);
        MFMA_BF16(af[m][1], b1r[n][1], acc[4 + m][2 + n]);
      }
    __builtin_amdgcn_s_setprio(0);
    __builtin_amdgcn_s_barrier();

    // ============ P3: stage A(t+2); mfma (1,0); boundary wait
    if (t + 2 < NT) stageA(t + 2);
    __builtin_amdgcn_s_barrier();
    __builtin_amdgcn_s_setprio(1);
#pragma unroll
    for (int m = 0; m < 4; ++m)
#pragma unroll
      for (int n = 0; n < 2; ++n) {
        MFMA_BF16(af[m][0], b0r[n][0], acc[4 + m][n]);
        MFMA_BF16(af[m][1], b0r[n][1], acc[4 + m][n]);
      }
    __builtin_amdgcn_s_setprio(0);
    if (t + 2 < NT)
      asm volatile("s_waitcnt vmcnt(8)\ns_barrier" ::: "memory");
    else if (t + 1 < NT)
      asm volatile("s_waitcnt vmcnt(0)\ns_barrier" ::: "memory");
  }

  if constexpr (sizeof(OUTT) == 2) {
    // ---- bf16: LDS-transpose epilogue. Swizzle: granule ^= (row>>2)&7.
    __syncthreads();                     // staging LDS now dead
#pragma unroll
    for (int nf = 0; nf < 4; ++nf) {
      const int col = wn * 64 + nf * 16 + fr;
      const float bv = bias[n0 + col];
#pragma unroll
      for (int mf = 0; mf < 8; ++mf) {
#pragma unroll
        for (int r = 0; r < 4; ++r) {
          const int row = wm * 128 + mf * 16 + (lane >> 4) * 4 + r;
          float v = acc[mf][nf][r] + bv;
          if (RELU) v = fmaxf(v, 0.f);
          lds[row * 256 + ((((col >> 3) ^ ((row >> 2) & 7)) << 3) | (col & 7))] =
              f2bf(v);
        }
      }
    }
    __syncthreads();
#pragma unroll
    for (int i = 0; i < 16; ++i) {
      const int ou = i * 4096 + tid * 8;          // u16 units
      const int row = ou >> 8;
      const int gp = (ou >> 3) & 31;
      const int cl = ((gp ^ ((row >> 2) & 7)) << 3);
      bf16x8 v = *(const bf16x8*)(lds + row * 256 + gp * 8);
      *(bf16x8*)&C[(size_t)(m0 + row) * N + n0 + cl] = v;
    }
  } else {
    // ---- f32: direct store path (64 B runs = full sectors)
#pragma unroll
    for (int nf = 0; nf < 4; ++nf) {
      const int col = n0 + wn * 64 + nf * 16 + fr;
      const float bv = bias[col];
#pragma unroll
      for (int mf = 0; mf < 8; ++mf) {
#pragma unroll
        for (int r = 0; r < 4; ++r) {
          const int row = m0 + wm * 128 + mf * 16 + (lane >> 4) * 4 + r;
          float v = acc[mf][nf][r] + bv;
          if (RELU) v = fmaxf(v, 0.f);
          C[(size_t)row * N + col] = v;
        }
      }
    }
  }
}

// ---------------------------------------------------------------------------
extern "C" void kernel_launch(void* const* d_in, const int* in_sizes, int n_in,
                              void* d_out, int out_size, void* d_ws, size_t ws_size,
                              hipStream_t stream) {
  const float* x     = (const float*)d_in[0];
  const float* noise = (const float*)d_in[1];
  const float* gw    = (const float*)d_in[2];
  const float* gn    = (const float*)d_in[3];
  const float* Wi    = (const float*)d_in[4];
  const float* bi    = (const float*)d_in[5];
  const float* Wo    = (const float*)d_in[6];
  const float* bo    = (const float*)d_in[7];
  float* out = (float*)d_out;

  char* w = (char*)d_ws;
  float* part    = (float*)(w + 0x000000);       // 512 KB: [1024][128]
  float* p2      = (float*)(w + 0x080000);       //  16 KB: [32][128]
  Sel*   sel     = (Sel*)  (w + 0x084000);       //  16 B
  float* bi_comb = (float*)(w + 0x084100);       //   8 KB
  float* bo_comb = (float*)(w + 0x086100);       //   4 KB
  u16*   gbT     = (u16*)  (w + 0x090000);       // 256 KB: [128][1024]
  u16*   xb      = (u16*)  (w + 0x0200000);      //  32 MB: [16384][1024]
  u16*   WiT     = (u16*)  (w + 0x2200000);      //   4 MB: [2048][1024]
  u16*   WoT     = (u16*)  (w + 0x2600000);      //   4 MB: [1024][2048]
  u16*   h       = (u16*)  (w + 0x2A00000);      //  64 MB: [16384][2048]

  cvt_gb<<<16, 256, 0, stream>>>(gw, gn, gbT);
  gate_fused<<<1024, 256, 0, stream>>>(x, gbT, xb, part);
  reduce_parts<<<32, 256, 0, stream>>>(part, p2);
  select_kernel<<<1, 256, 0, stream>>>(p2, noise, bi, bo, sel, bi_comb, bo_comb);
  prep_weights<<<1024, 256, 0, stream>>>(Wi, Wo, sel, WiT, WoT);
  // GEMM1: [16384,1024] x [1024,2048] -> h ; grid 64x8 = 512
  gemm256<1, u16>  <<<512, 512, 0, stream>>>(xb, WiT, bi_comb, h, 2048, 1024, 8);
  // GEMM2: [16384,2048] x [2048,1024] -> out ; grid 64x4 = 256
  gemm256<0, float><<<256, 512, 0, stream>>>(h, WoT, bo_comb, out, 1024, 2048, 4);
}

// Round 10
// 202.020 us; speedup vs baseline: 1.0587x; 1.0587x over previous
//
#include <hip/hip_runtime.h>
#include <cstdint>
#include <cstddef>

#define DI __device__ __forceinline__

typedef __attribute__((ext_vector_type(8))) short bf16x8;   // 8 bf16 in 4 VGPRs
typedef __attribute__((ext_vector_type(4))) float f32x4;
using u16 = unsigned short;

struct Sel { int i0, i1; float g0, g1; };

DI u16 f2bf(float f) {
  union { float f; unsigned u; } c; c.f = f;
  unsigned u = c.u;
  unsigned r = (u + 0x7fffu + ((u >> 16) & 1u)) >> 16;   // RNE
  return (u16)r;
}

DI float softplus_f(float z) {
  return (z > 0.f) ? (z + log1pf(expf(-z))) : log1pf(expf(z));
}

DI void async16(const void* g, void* l) {
  __builtin_amdgcn_global_load_lds(
      (const __attribute__((address_space(1))) unsigned int*)g,
      (__attribute__((address_space(3))) unsigned int*)l, 16, 0, 0);
}

#define MFMA_BF16(a, b, c) \
  c = __builtin_amdgcn_mfma_f32_16x16x32_bf16(a, b, c, 0, 0, 0)

// ---------------------------------------------------------------------------
// cvt_gb: gn,gw [1024i][64e] f32 -> gbT [128][1024] bf16 (rows 0-63 = gn^T,
// rows 64-127 = gw^T), granule-swizzled: elem col i stored at granule
// (i>>3) ^ (e&7), so the gate's LDS B-reads are bank-spread. 16 blocks.
// ---------------------------------------------------------------------------
__global__ __launch_bounds__(256) void cvt_gb(
    const float* __restrict__ gw, const float* __restrict__ gn,
    u16* __restrict__ gbT) {
  __shared__ float tile[64][65];
  const int tid = threadIdx.x;
  const int i0 = blockIdx.x * 64;
  for (int pass = 0; pass < 2; ++pass) {
    const float* src = pass ? gw : gn;
    if (pass) __syncthreads();
#pragma unroll
    for (int j = 0; j < 16; ++j) {
      int lin = j * 256 + tid;
      int r = lin >> 6, c = lin & 63;
      tile[r][c] = src[(size_t)(i0 + r) * 64 + c];
    }
    __syncthreads();
#pragma unroll
    for (int j = 0; j < 16; ++j) {
      int lin = j * 256 + tid;
      int e = lin >> 6, r2 = lin & 63;
      int i = i0 + r2;
      int col = ((((i >> 3) ^ (e & 7)) << 3) | (i & 7));
      gbT[(size_t)(pass * 64 + e) * 1024 + col] = f2bf(tile[r2][e]);
    }
  }
}

// ---------------------------------------------------------------------------
// gate_fused: 1024 blocks x 256 thr, 16 tokens each. LDS = 64 KB (2 blk/CU).
// gbT staging issued BEFORE the x-stream so its latency hides; Phase-A
// ends with vmcnt(32) (tiles 0-1 landed; xb stores may still be in flight).
// ---------------------------------------------------------------------------
__global__ __launch_bounds__(256) void gate_fused(
    const float* __restrict__ x, const u16* __restrict__ gbT,
    u16* __restrict__ xb, float* __restrict__ part) {
  __shared__ u16 smX[16 * 1024];        // 32 KB
  __shared__ u16 smG[2][128 * 64];      // 32 KB
  const int tid = threadIdx.x;
  const int wave = tid >> 6, lane = tid & 63;
  const int tok0 = blockIdx.x * 16;

  auto stageG = [&](int t) {
    const u16* base = gbT + (size_t)t * 64;
#pragma unroll
    for (int j = 0; j < 4; ++j) {
      int chunk = j * 256 + wave * 64 + lane;
      const u16* g = base + (size_t)(chunk >> 3) * 1024 + (chunk & 7) * 8;
      async16(g, &smG[t & 1][(size_t)(j * 256 + wave * 64) * 8]);
    }
  };

  stageG(0);
  stageG(1);

  // ---- Phase A: stream + convert (thread owns 4 cols x 16 rows)
  {
    const int c0 = tid * 4;
    const int g = c0 >> 3, sub = c0 & 7;
#pragma unroll 4
    for (int r = 0; r < 16; ++r) {
      float4 v = *(const float4*)&x[(size_t)(tok0 + r) * 1024 + c0];
      ushort4 o; o.x = f2bf(v.x); o.y = f2bf(v.y); o.z = f2bf(v.z); o.w = f2bf(v.w);
      *(ushort4*)&xb[(size_t)(tok0 + r) * 1024 + c0] = o;
      const int sc = (((g ^ (r & 7)) << 3) | sub);
      *(ushort4*)&smX[r * 1024 + sc] = o;
    }
  }

  // tiles 0-1 landed (first 8 vm-ops retired, in-order); smX writes drained
  asm volatile("s_waitcnt vmcnt(32) lgkmcnt(0)" ::: "memory");
  __builtin_amdgcn_s_barrier();

  const int fr = lane & 15;
  const int q = lane >> 4;
  const int f7 = fr & 7;

  f32x4 acc[2] = {};   // f = 0,1 -> experts wave*32 + f*16 + fr

  for (int t = 0; t < 16; ++t) {
    const u16* Gb = &smG[t & 1][0];
    bf16x8 a0, a1, b0[2], b1[2];
    {
      const int arow = fr * 1024;
      a0 = *(const bf16x8*)(smX + arow + (((t * 8 + q) ^ f7) << 3));
      a1 = *(const bf16x8*)(smX + arow + (((t * 8 + 4 + q) ^ f7) << 3));
    }
#pragma unroll
    for (int f = 0; f < 2; ++f) {
      const int rb = (wave * 32 + f * 16 + fr) * 64;
      b0[f] = *(const bf16x8*)(Gb + rb + ((q ^ f7) << 3));
      b1[f] = *(const bf16x8*)(Gb + rb + (((4 + q) ^ f7) << 3));
    }
    asm volatile("s_waitcnt lgkmcnt(0)" ::: "memory");
    __builtin_amdgcn_sched_barrier(0);
    __builtin_amdgcn_s_barrier();       // all waves done reading buf (t&1)
    if (t + 2 < 16) stageG(t + 2);
    __builtin_amdgcn_s_setprio(1);
    MFMA_BF16(a0, b0[0], acc[0]);
    MFMA_BF16(a1, b1[0], acc[0]);
    MFMA_BF16(a0, b0[1], acc[1]);
    MFMA_BF16(a1, b1[1], acc[1]);
    __builtin_amdgcn_s_setprio(0);
    if (t + 2 < 16)
      asm volatile("s_waitcnt vmcnt(4)\ns_barrier" ::: "memory");
    else if (t == 14)
      asm volatile("s_waitcnt vmcnt(0)\ns_barrier" ::: "memory");
  }

  // C layout: expert = wave*32 + f*16 + fr ; token = q*4 + reg.
#pragma unroll
  for (int f = 0; f < 2; ++f) {
    float s;
    if (wave < 2)
      s = softplus_f(acc[f][0]) + softplus_f(acc[f][1]) +
          softplus_f(acc[f][2]) + softplus_f(acc[f][3]);
    else
      s = (acc[f][0] + acc[f][1]) + (acc[f][2] + acc[f][3]);
    s += __shfl_xor(s, 16);
    s += __shfl_xor(s, 32);
    if (q == 0)
      part[(size_t)blockIdx.x * 128 + wave * 32 + f * 16 + fr] = s;
  }
}

// ---------------------------------------------------------------------------
// reduce_parts: [1024][128] -> [32][128]. 32 blocks x 256 thr.
// ---------------------------------------------------------------------------
__global__ __launch_bounds__(256) void reduce_parts(
    const float* __restrict__ part, float* __restrict__ p2) {
  __shared__ float rs[2][128];
  const int bb = blockIdx.x, tid = threadIdx.x;
  const int idx = tid & 127, sub = tid >> 7;
  const float* src = part + (size_t)(bb * 32 + sub * 16) * 128 + idx;
  float s0 = 0.f, s1 = 0.f, s2 = 0.f, s3 = 0.f;
#pragma unroll
  for (int j = 0; j < 16; j += 4) {
    s0 += src[(j + 0) * 128];
    s1 += src[(j + 1) * 128];
    s2 += src[(j + 2) * 128];
    s3 += src[(j + 3) * 128];
  }
  rs[sub][idx] = (s0 + s1) + (s2 + s3);
  __syncthreads();
  if (sub == 0) p2[(size_t)bb * 128 + idx] = rs[0][idx] + rs[1][idx];
}

// ---------------------------------------------------------------------------
// select: reduce 32 partials, mean logits, top-2, gates, combined biases.
// ---------------------------------------------------------------------------
__global__ __launch_bounds__(256) void select_kernel(
    const float* __restrict__ p2, const float* __restrict__ noise,
    const float* __restrict__ bi, const float* __restrict__ bo,
    Sel* __restrict__ sel_out, float* __restrict__ bi_comb,
    float* __restrict__ bo_comb) {
  __shared__ float sums[128];
  __shared__ float ml[64];
  __shared__ Sel sl;
  const int tid = threadIdx.x;
  if (tid < 128) {
    float s0 = 0.f, s1 = 0.f, s2 = 0.f, s3 = 0.f;
#pragma unroll
    for (int b = 0; b < 32; b += 4) {
      s0 += p2[(b + 0) * 128 + tid];
      s1 += p2[(b + 1) * 128 + tid];
      s2 += p2[(b + 2) * 128 + tid];
      s3 += p2[(b + 3) * 128 + tid];
    }
    sums[tid] = (s0 + s1) + (s2 + s3);
  }
  __syncthreads();
  if (tid < 64)
    ml[tid] = (sums[64 + tid] + sums[tid] * noise[tid]) * (1.f / 16384.f);
  __syncthreads();
  if (tid == 0) {
    int i0 = 0; float v0 = ml[0];
    for (int e2 = 1; e2 < 64; ++e2) if (ml[e2] > v0) { v0 = ml[e2]; i0 = e2; }
    int i1 = (i0 == 0) ? 1 : 0; float v1 = ml[i1];
    for (int e2 = 0; e2 < 64; ++e2)
      if (e2 != i0 && ml[e2] > v1) { v1 = ml[e2]; i1 = e2; }
    float e1 = expf(v1 - v0);                 // softmax over [v0, v1]
    float inv = 1.f / (1.f + e1);
    Sel s; s.i0 = i0; s.i1 = i1; s.g0 = inv; s.g1 = e1 * inv;
    sl = s; *sel_out = s;
  }
  __syncthreads();
  Sel s = sl;
  for (int n = tid; n < 2048; n += 256) {
    int ei = (n < 1024) ? s.i0 : s.i1;
    bi_comb[n] = bi[ei * 1024 + (n & 1023)];
  }
  for (int o = tid; o < 1024; o += 256)
    bo_comb[o] = s.g0 * bo[s.i0 * 1024 + o] + s.g1 * bo[s.i1 * 1024 + o];
}

// ---------------------------------------------------------------------------
// Transpose + bf16-convert selected expert weights. (unchanged)
// ---------------------------------------------------------------------------
__global__ __launch_bounds__(256) void prep_weights(
    const float* __restrict__ Wi, const float* __restrict__ Wo,
    const Sel* __restrict__ selp, u16* __restrict__ WiT, u16* __restrict__ WoT) {
  __shared__ float tile[64][65];
  Sel s = *selp;
  const int bid = blockIdx.x;
  const float* src; float scale; u16* dst; int dld, dr0, dc0;
  if (bid < 512) {
    int tn = bid >> 4, ti = bid & 15;           // 32 n-tiles x 16 i-tiles
    int n0 = tn * 64, i0 = ti * 64;
    int k = n0 >> 10, h0 = n0 & 1023;
    int e = k ? s.i1 : s.i0;
    src = Wi + (size_t)e * 1024 * 1024 + (size_t)i0 * 1024 + h0; // [r=i][c=h]
    scale = 1.f; dst = WiT; dld = 1024; dr0 = n0; dc0 = i0;
  } else {
    int b2 = bid - 512;
    int ro = b2 >> 5, ck = b2 & 31;             // 16 o-tiles x 32 kc-tiles
    int o0 = ro * 64, kc0 = ck * 64;
    int k = kc0 >> 10, h0 = kc0 & 1023;
    int e = k ? s.i1 : s.i0;
    scale = k ? s.g1 : s.g0;
    src = Wo + (size_t)e * 1024 * 1024 + (size_t)h0 * 1024 + o0; // [r=hh][c=o]
    dst = WoT; dld = 2048; dr0 = o0; dc0 = kc0;
  }
  const int tid = threadIdx.x;
#pragma unroll
  for (int j = 0; j < 4; ++j) {
    int lin = j * 256 + tid;
    int r = lin >> 4, c4 = (lin & 15) * 4;
    float4 v = *(const float4*)&src[(size_t)r * 1024 + c4];
    tile[r][c4] = v.x; tile[r][c4 + 1] = v.y; tile[r][c4 + 2] = v.z; tile[r][c4 + 3] = v.w;
  }
  __syncthreads();
#pragma unroll
  for (int j = 0; j < 4; ++j) {
    int lin = j * 256 + tid;
    int r2 = lin >> 4, c2 = (lin & 15) * 4;     // r2: out row, c2: out col
    ushort4 o;
    o.x = f2bf(scale * tile[c2][r2]);
    o.y = f2bf(scale * tile[c2 + 1][r2]);
    o.z = f2bf(scale * tile[c2 + 2][r2]);
    o.w = f2bf(scale * tile[c2 + 3][r2]);
    *(ushort4*)&dst[(size_t)(dr0 + r2) * dld + dc0 + c2] = o;
  }
}

// ---------------------------------------------------------------------------
// 256x256 8-phase bf16 GEMM (r5 schedule + r8 LDS-transpose epilogue for
// bf16 output).
// ---------------------------------------------------------------------------
template <int RELU, typename OUTT>
__global__ __launch_bounds__(512) void gemm256(
    const u16* __restrict__ A, const u16* __restrict__ Bt,
    const float* __restrict__ bias, OUTT* __restrict__ C,
    int N, int K, int nN) {
  __shared__ u16 lds[65536];            // [0,32K): A dbuf | [32K,64K): B dbuf
  const int tid = threadIdx.x;
  const int wave = tid >> 6, lane = tid & 63;

  // XCD-aware bijective remap (gridDim.x % 8 == 0)
  const int cpx = gridDim.x >> 3;
  const int wg = (blockIdx.x & 7) * cpx + (blockIdx.x >> 3);
  const int m0 = (wg / nN) * 256, n0 = (wg % nN) * 256;
  const int wm = wave >> 2, wn = wave & 3;

  f32x4 acc[8][4] = {};

  const int srow = wave * 8 + (lane >> 3);
  const int gcol = (((lane & 7) ^ ((lane >> 3) & 7)) << 3);
  const u16* gA = A + (size_t)(m0 + srow) * K + gcol;
  const u16* gB = Bt + (size_t)(n0 + srow) * K + gcol;
  const int ldsOff = wave * 512;

  const int NT = K >> 6;

  auto stageA = [&](int t) {
    const u16* a = gA + t * 64;
    u16* la = lds + (t & 1) * 16384 + ldsOff;
#pragma unroll
    for (int j = 0; j < 4; ++j) async16(a + (size_t)j * 64 * K, la + j * 4096);
  };
  auto stageB = [&](int t) {
    const u16* b = gB + t * 64;
    u16* lb = lds + 32768 + (t & 1) * 16384 + ldsOff;
#pragma unroll
    for (int j = 0; j < 4; ++j) async16(b + (size_t)j * 64 * K, lb + j * 4096);
  };

  stageB(0); stageA(0);
  stageB(1); stageA(1);
  asm volatile("s_waitcnt vmcnt(8)\ns_barrier" ::: "memory");

  const int fr = lane & 15;
  const int cx = (lane & 7) << 3;
  const int cb0 = (((lane >> 4) << 3)) ^ cx;        // kk=0 col (elems)
  const int cb1 = (32 | ((lane >> 4) << 3)) ^ cx;   // kk=1 col (elems)

  bf16x8 af[4][2], b0r[2][2], b1r[2][2];

  for (int t = 0; t < NT; ++t) {
    const u16* Ab = lds + (t & 1) * 16384;
    const u16* Bb = lds + 32768 + (t & 1) * 16384;

    // ============ P0: read A[mq=0], B[nq=0]; mfma (0,0)
#pragma unroll
    for (int m = 0; m < 4; ++m) {
      const int rA = (wm * 128 + m * 16 + fr) * 64;
      af[m][0] = *(const bf16x8*)(Ab + rA + cb0);
      af[m][1] = *(const bf16x8*)(Ab + rA + cb1);
    }
#pragma unroll
    for (int n = 0; n < 2; ++n) {
      const int rB = (wn * 64 + n * 16 + fr) * 64;
      b0r[n][0] = *(const bf16x8*)(Bb + rB + cb0);
      b0r[n][1] = *(const bf16x8*)(Bb + rB + cb1);
    }
    __builtin_amdgcn_s_barrier();
    asm volatile("s_waitcnt lgkmcnt(0)" ::: "memory");
    __builtin_amdgcn_sched_barrier(0);
    __builtin_amdgcn_s_setprio(1);
#pragma unroll
    for (int m = 0; m < 4; ++m)
#pragma unroll
      for (int n = 0; n < 2; ++n) {
        MFMA_BF16(af[m][0], b0r[n][0], acc[m][n]);
        MFMA_BF16(af[m][1], b0r[n][1], acc[m][n]);
      }
    __builtin_amdgcn_s_setprio(0);
    __builtin_amdgcn_s_barrier();

    // ============ P1: read B[nq=1]; mfma (0,1)
#pragma unroll
    for (int n = 0; n < 2; ++n) {
      const int rB = (wn * 64 + 32 + n * 16 + fr) * 64;
      b1r[n][0] = *(const bf16x8*)(Bb + rB + cb0);
      b1r[n][1] = *(const bf16x8*)(Bb + rB + cb1);
    }
    __builtin_amdgcn_s_barrier();
    asm volatile("s_waitcnt lgkmcnt(0)" ::: "memory");
    __builtin_amdgcn_sched_barrier(0);
    __builtin_amdgcn_s_setprio(1);
#pragma unroll
    for (int m = 0; m < 4; ++m)
#pragma unroll
      for (int n = 0; n < 2; ++n) {
        MFMA_BF16(af[m][0], b1r[n][0], acc[m][2 + n]);
        MFMA_BF16(af[m][1], b1r[n][1], acc[m][2 + n]);
      }
    __builtin_amdgcn_s_setprio(0);
    __builtin_amdgcn_s_barrier();

    // ============ P2: read A[mq=1]; stage B(t+2); mfma (1,1)
#pragma unroll
    for (int m = 0; m < 4; ++m) {
      const int rA = (wm * 128 + 64 + m * 16 + fr) * 64;
      af[m][0] = *(const bf16x8*)(Ab + rA + cb0);
      af[m][1] = *(const bf16x8*)(Ab + rA + cb1);
    }
    if (t + 2 < NT) stageB(t + 2);
    __builtin_amdgcn_s_barrier();
    asm volatile("s_waitcnt lgkmcnt(0)" ::: "memory");
    __builtin_amdgcn_sched_barrier(0);
    __builtin_amdgcn_s_setprio(1);
#pragma unroll
    for (int m = 0; m < 4; ++m)
#pragma unroll
      for (int n = 0; n < 2; ++n) {
        MFMA_BF16(af[m][0], b1r[n][0], acc[4 + m][2 + n]);
        MFMA_BF16(af[m][1], b1r[n][1], acc[4 + m][2 + n]);
      }
    __builtin_amdgcn_s_setprio(0);
    __builtin_amdgcn_s_barrier();

    // ============ P3: stage A(t+2); mfma (1,0); boundary wait
    if (t + 2 < NT) stageA(t + 2);
    __builtin_amdgcn_s_barrier();
    __builtin_amdgcn_s_setprio(1);
#pragma unroll
    for (int m = 0; m < 4; ++m)
#pragma unroll
      for (int n = 0; n < 2; ++n) {
        MFMA_BF16(af[m][0], b0r[n][0], acc[4 + m][n]);
        MFMA_BF16(af[m][1], b0r[n][1], acc[4 + m][n]);
      }
    __builtin_amdgcn_s_setprio(0);
    if (t + 2 < NT)
      asm volatile("s_waitcnt vmcnt(8)\ns_barrier" ::: "memory");
    else if (t + 1 < NT)
      asm volatile("s_waitcnt vmcnt(0)\ns_barrier" ::: "memory");
  }

  if constexpr (sizeof(OUTT) == 2) {
    // ---- bf16: LDS-transpose epilogue. Swizzle: granule ^= (row>>2)&7.
    __syncthreads();                     // staging LDS now dead
#pragma unroll
    for (int nf = 0; nf < 4; ++nf) {
      const int col = wn * 64 + nf * 16 + fr;
      const float bv = bias[n0 + col];
#pragma unroll
      for (int mf = 0; mf < 8; ++mf) {
#pragma unroll
        for (int r = 0; r < 4; ++r) {
          const int row = wm * 128 + mf * 16 + (lane >> 4) * 4 + r;
          float v = acc[mf][nf][r] + bv;
          if (RELU) v = fmaxf(v, 0.f);
          lds[row * 256 + ((((col >> 3) ^ ((row >> 2) & 7)) << 3) | (col & 7))] =
              f2bf(v);
        }
      }
    }
    __syncthreads();
#pragma unroll
    for (int i = 0; i < 16; ++i) {
      const int ou = i * 4096 + tid * 8;          // u16 units
      const int row = ou >> 8;
      const int gp = (ou >> 3) & 31;
      const int cl = ((gp ^ ((row >> 2) & 7)) << 3);
      bf16x8 v = *(const bf16x8*)(lds + row * 256 + gp * 8);
      *(bf16x8*)&C[(size_t)(m0 + row) * N + n0 + cl] = v;
    }
  } else {
    // ---- f32: direct store path (64 B runs = full sectors)
#pragma unroll
    for (int nf = 0; nf < 4; ++nf) {
      const int col = n0 + wn * 64 + nf * 16 + fr;
      const float bv = bias[col];
#pragma unroll
      for (int mf = 0; mf < 8; ++mf) {
#pragma unroll
        for (int r = 0; r < 4; ++r) {
          const int row = m0 + wm * 128 + mf * 16 + (lane >> 4) * 4 + r;
          float v = acc[mf][nf][r] + bv;
          if (RELU) v = fmaxf(v, 0.f);
          C[(size_t)row * N + col] = v;
        }
      }
    }
  }
}

// ---------------------------------------------------------------------------
extern "C" void kernel_launch(void* const* d_in, const int* in_sizes, int n_in,
                              void* d_out, int out_size, void* d_ws, size_t ws_size,
                              hipStream_t stream) {
  const float* x     = (const float*)d_in[0];
  const float* noise = (const float*)d_in[1];
  const float* gw    = (const float*)d_in[2];
  const float* gn    = (const float*)d_in[3];
  const float* Wi    = (const float*)d_in[4];
  const float* bi    = (const float*)d_in[5];
  const float* Wo    = (const float*)d_in[6];
  const float* bo    = (const float*)d_in[7];
  float* out = (float*)d_out;

  char* w = (char*)d_ws;
  float* part    = (float*)(w + 0x000000);       // 512 KB: [1024][128]
  float* p2      = (float*)(w + 0x080000);       //  16 KB: [32][128]
  Sel*   sel     = (Sel*)  (w + 0x084000);       //  16 B
  float* bi_comb = (float*)(w + 0x084100);       //   8 KB
  float* bo_comb = (float*)(w + 0x086100);       //   4 KB
  u16*   gbT     = (u16*)  (w + 0x090000);       // 256 KB: [128][1024] (pre-swizzled)
  u16*   xb      = (u16*)  (w + 0x0200000);      //  32 MB: [16384][1024]
  u16*   WiT     = (u16*)  (w + 0x2200000);      //   4 MB: [2048][1024]
  u16*   WoT     = (u16*)  (w + 0x2600000);      //   4 MB: [1024][2048]
  u16*   h       = (u16*)  (w + 0x2A00000);      //  64 MB: [16384][2048]

  cvt_gb<<<16, 256, 0, stream>>>(gw, gn, gbT);
  gate_fused<<<1024, 256, 0, stream>>>(x, gbT, xb, part);
  reduce_parts<<<32, 256, 0, stream>>>(part, p2);
  select_kernel<<<1, 256, 0, stream>>>(p2, noise, bi, bo, sel, bi_comb, bo_comb);
  prep_weights<<<1024, 256, 0, stream>>>(Wi, Wo, sel, WiT, WoT);
  // GEMM1: [16384,1024] x [1024,2048] -> h ; grid 64x8 = 512
  gemm256<1, u16>  <<<512, 512, 0, stream>>>(xb, WiT, bi_comb, h, 2048, 1024, 8);
  // GEMM2: [16384,2048] x [2048,1024] -> out ; grid 64x4 = 256
  gemm256<0, float><<<256, 512, 0, stream>>>(h, WoT, bo_comb, out, 1024, 2048, 4);
}

// Round 11
// 199.798 us; speedup vs baseline: 1.0705x; 1.0111x over previous
//
#include <hip/hip_runtime.h>
#include <cstdint>
#include <cstddef>

#define DI __device__ __forceinline__

typedef __attribute__((ext_vector_type(8))) short bf16x8;   // 8 bf16 in 4 VGPRs
typedef __attribute__((ext_vector_type(4))) float f32x4;
using u16 = unsigned short;

struct Sel { int i0, i1; float g0, g1; };

DI u16 f2bf(float f) {
  union { float f; unsigned u; } c; c.f = f;
  unsigned u = c.u;
  unsigned r = (u + 0x7fffu + ((u >> 16) & 1u)) >> 16;   // RNE
  return (u16)r;
}

DI float softplus_f(float z) {
  return (z > 0.f) ? (z + log1pf(expf(-z))) : log1pf(expf(z));
}

DI void async16(const void* g, void* l) {
  __builtin_amdgcn_global_load_lds(
      (const __attribute__((address_space(1))) unsigned int*)g,
      (__attribute__((address_space(3))) unsigned int*)l, 16, 0, 0);
}

#define MFMA_BF16(a, b, c) \
  c = __builtin_amdgcn_mfma_f32_16x16x32_bf16(a, b, c, 0, 0, 0)

// ---------------------------------------------------------------------------
// cvt_gb: gn,gw [1024i][64e] f32 -> gbT [128][1024] bf16 (rows 0-63 = gn^T,
// rows 64-127 = gw^T), granule-swizzled: elem col i stored at granule
// (i>>3) ^ (e&7), so the gate's LDS B-reads are bank-spread. 16 blocks.
// ---------------------------------------------------------------------------
__global__ __launch_bounds__(256) void cvt_gb(
    const float* __restrict__ gw, const float* __restrict__ gn,
    u16* __restrict__ gbT) {
  __shared__ float tile[64][65];
  const int tid = threadIdx.x;
  const int i0 = blockIdx.x * 64;
  for (int pass = 0; pass < 2; ++pass) {
    const float* src = pass ? gw : gn;
    if (pass) __syncthreads();
#pragma unroll
    for (int j = 0; j < 16; ++j) {
      int lin = j * 256 + tid;
      int r = lin >> 6, c = lin & 63;
      tile[r][c] = src[(size_t)(i0 + r) * 64 + c];
    }
    __syncthreads();
#pragma unroll
    for (int j = 0; j < 16; ++j) {
      int lin = j * 256 + tid;
      int e = lin >> 6, r2 = lin & 63;
      int i = i0 + r2;
      int col = ((((i >> 3) ^ (e & 7)) << 3) | (i & 7));
      gbT[(size_t)(pass * 64 + e) * 1024 + col] = f2bf(tile[r2][e]);
    }
  }
}

// ---------------------------------------------------------------------------
// gate_fused: 1024 blocks x 256 thr, 16 tokens each. LDS = 80 KB (2 blk/CU).
// Phase B now triple-buffers gbT tiles (prefetch distance 3) so staging L2
// latency is covered by ~2 iterations of the short MFMA loop.
// ---------------------------------------------------------------------------
__global__ __launch_bounds__(256) void gate_fused(
    const float* __restrict__ x, const u16* __restrict__ gbT,
    u16* __restrict__ xb, float* __restrict__ part) {
  __shared__ u16 smX[16 * 1024];        // 32 KB
  __shared__ u16 smG[3][128 * 64];      // 48 KB
  const int tid = threadIdx.x;
  const int wave = tid >> 6, lane = tid & 63;
  const int tok0 = blockIdx.x * 16;

  auto stageG = [&](int t) {
    const u16* base = gbT + (size_t)t * 64;
    u16* dst = &smG[t % 3][0];
#pragma unroll
    for (int j = 0; j < 4; ++j) {
      int chunk = j * 256 + wave * 64 + lane;
      const u16* g = base + (size_t)(chunk >> 3) * 1024 + (chunk & 7) * 8;
      async16(g, dst + (size_t)(j * 256 + wave * 64) * 8);
    }
  };

  stageG(0);
  stageG(1);
  stageG(2);

  // ---- Phase A: stream + convert (thread owns 4 cols x 16 rows)
  {
    const int c0 = tid * 4;
    const int g = c0 >> 3, sub = c0 & 7;
#pragma unroll 4
    for (int r = 0; r < 16; ++r) {
      float4 v = *(const float4*)&x[(size_t)(tok0 + r) * 1024 + c0];
      ushort4 o; o.x = f2bf(v.x); o.y = f2bf(v.y); o.z = f2bf(v.z); o.w = f2bf(v.w);
      *(ushort4*)&xb[(size_t)(tok0 + r) * 1024 + c0] = o;
      const int sc = (((g ^ (r & 7)) << 3) | sub);
      *(ushort4*)&smX[r * 1024 + sc] = o;
    }
  }

  // 44 vm-ops issued/wave (12 stage + 32 phase-A); <=32 outstanding ==>
  // oldest 12 (all staging, tiles 0-2) retired. smX ds_writes drained.
  asm volatile("s_waitcnt vmcnt(32) lgkmcnt(0)" ::: "memory");
  __builtin_amdgcn_s_barrier();

  const int fr = lane & 15;
  const int q = lane >> 4;
  const int f7 = fr & 7;

  f32x4 acc[2] = {};   // f = 0,1 -> experts wave*32 + f*16 + fr

  for (int t = 0; t < 16; ++t) {
    const u16* Gb = &smG[t % 3][0];
    bf16x8 a0, a1, b0[2], b1[2];
    {
      const int arow = fr * 1024;
      a0 = *(const bf16x8*)(smX + arow + (((t * 8 + q) ^ f7) << 3));
      a1 = *(const bf16x8*)(smX + arow + (((t * 8 + 4 + q) ^ f7) << 3));
    }
#pragma unroll
    for (int f = 0; f < 2; ++f) {
      const int rb = (wave * 32 + f * 16 + fr) * 64;
      b0[f] = *(const bf16x8*)(Gb + rb + ((q ^ f7) << 3));
      b1[f] = *(const bf16x8*)(Gb + rb + (((4 + q) ^ f7) << 3));
    }
    asm volatile("s_waitcnt lgkmcnt(0)" ::: "memory");
    __builtin_amdgcn_sched_barrier(0);
    __builtin_amdgcn_s_barrier();       // all waves done reading buf (t%3)
    if (t + 3 < 16) stageG(t + 3);      // overwrites buf (t%3) -- safe now
    __builtin_amdgcn_s_setprio(1);
    MFMA_BF16(a0, b0[0], acc[0]);
    MFMA_BF16(a1, b1[0], acc[0]);
    MFMA_BF16(a0, b0[1], acc[1]);
    MFMA_BF16(a1, b1[1], acc[1]);
    __builtin_amdgcn_s_setprio(0);
    // ensure tile t+1 landed (in-order retirement): allowed outstanding =
    // 4 * (#tiles staged beyond t+1) = 8 (t<=12) / 4 (t=13) / 0 (t=14).
    if (t <= 12)
      asm volatile("s_waitcnt vmcnt(8)\ns_barrier" ::: "memory");
    else if (t == 13)
      asm volatile("s_waitcnt vmcnt(4)\ns_barrier" ::: "memory");
    else if (t == 14)
      asm volatile("s_waitcnt vmcnt(0)\ns_barrier" ::: "memory");
  }

  // C layout: expert = wave*32 + f*16 + fr ; token = q*4 + reg.
#pragma unroll
  for (int f = 0; f < 2; ++f) {
    float s;
    if (wave < 2)
      s = softplus_f(acc[f][0]) + softplus_f(acc[f][1]) +
          softplus_f(acc[f][2]) + softplus_f(acc[f][3]);
    else
      s = (acc[f][0] + acc[f][1]) + (acc[f][2] + acc[f][3]);
    s += __shfl_xor(s, 16);
    s += __shfl_xor(s, 32);
    if (q == 0)
      part[(size_t)blockIdx.x * 128 + wave * 32 + f * 16 + fr] = s;
  }
}

// ---------------------------------------------------------------------------
// reduce_parts: [1024][128] -> [32][128]. 32 blocks x 256 thr.
// ---------------------------------------------------------------------------
__global__ __launch_bounds__(256) void reduce_parts(
    const float* __restrict__ part, float* __restrict__ p2) {
  __shared__ float rs[2][128];
  const int bb = blockIdx.x, tid = threadIdx.x;
  const int idx = tid & 127, sub = tid >> 7;
  const float* src = part + (size_t)(bb * 32 + sub * 16) * 128 + idx;
  float s0 = 0.f, s1 = 0.f, s2 = 0.f, s3 = 0.f;
#pragma unroll
  for (int j = 0; j < 16; j += 4) {
    s0 += src[(j + 0) * 128];
    s1 += src[(j + 1) * 128];
    s2 += src[(j + 2) * 128];
    s3 += src[(j + 3) * 128];
  }
  rs[sub][idx] = (s0 + s1) + (s2 + s3);
  __syncthreads();
  if (sub == 0) p2[(size_t)bb * 128 + idx] = rs[0][idx] + rs[1][idx];
}

// ---------------------------------------------------------------------------
// select: reduce 32 partials, mean logits, top-2, gates, combined biases.
// ---------------------------------------------------------------------------
__global__ __launch_bounds__(256) void select_kernel(
    const float* __restrict__ p2, const float* __restrict__ noise,
    const float* __restrict__ bi, const float* __restrict__ bo,
    Sel* __restrict__ sel_out, float* __restrict__ bi_comb,
    float* __restrict__ bo_comb) {
  __shared__ float sums[128];
  __shared__ float ml[64];
  __shared__ Sel sl;
  const int tid = threadIdx.x;
  if (tid < 128) {
    float s0 = 0.f, s1 = 0.f, s2 = 0.f, s3 = 0.f;
#pragma unroll
    for (int b = 0; b < 32; b += 4) {
      s0 += p2[(b + 0) * 128 + tid];
      s1 += p2[(b + 1) * 128 + tid];
      s2 += p2[(b + 2) * 128 + tid];
      s3 += p2[(b + 3) * 128 + tid];
    }
    sums[tid] = (s0 + s1) + (s2 + s3);
  }
  __syncthreads();
  if (tid < 64)
    ml[tid] = (sums[64 + tid] + sums[tid] * noise[tid]) * (1.f / 16384.f);
  __syncthreads();
  if (tid == 0) {
    int i0 = 0; float v0 = ml[0];
    for (int e2 = 1; e2 < 64; ++e2) if (ml[e2] > v0) { v0 = ml[e2]; i0 = e2; }
    int i1 = (i0 == 0) ? 1 : 0; float v1 = ml[i1];
    for (int e2 = 0; e2 < 64; ++e2)
      if (e2 != i0 && ml[e2] > v1) { v1 = ml[e2]; i1 = e2; }
    float e1 = expf(v1 - v0);                 // softmax over [v0, v1]
    float inv = 1.f / (1.f + e1);
    Sel s; s.i0 = i0; s.i1 = i1; s.g0 = inv; s.g1 = e1 * inv;
    sl = s; *sel_out = s;
  }
  __syncthreads();
  Sel s = sl;
  for (int n = tid; n < 2048; n += 256) {
    int ei = (n < 1024) ? s.i0 : s.i1;
    bi_comb[n] = bi[ei * 1024 + (n & 1023)];
  }
  for (int o = tid; o < 1024; o += 256)
    bo_comb[o] = s.g0 * bo[s.i0 * 1024 + o] + s.g1 * bo[s.i1 * 1024 + o];
}

// ---------------------------------------------------------------------------
// Transpose + bf16-convert selected expert weights. (unchanged)
// ---------------------------------------------------------------------------
__global__ __launch_bounds__(256) void prep_weights(
    const float* __restrict__ Wi, const float* __restrict__ Wo,
    const Sel* __restrict__ selp, u16* __restrict__ WiT, u16* __restrict__ WoT) {
  __shared__ float tile[64][65];
  Sel s = *selp;
  const int bid = blockIdx.x;
  const float* src; float scale; u16* dst; int dld, dr0, dc0;
  if (bid < 512) {
    int tn = bid >> 4, ti = bid & 15;           // 32 n-tiles x 16 i-tiles
    int n0 = tn * 64, i0 = ti * 64;
    int k = n0 >> 10, h0 = n0 & 1023;
    int e = k ? s.i1 : s.i0;
    src = Wi + (size_t)e * 1024 * 1024 + (size_t)i0 * 1024 + h0; // [r=i][c=h]
    scale = 1.f; dst = WiT; dld = 1024; dr0 = n0; dc0 = i0;
  } else {
    int b2 = bid - 512;
    int ro = b2 >> 5, ck = b2 & 31;             // 16 o-tiles x 32 kc-tiles
    int o0 = ro * 64, kc0 = ck * 64;
    int k = kc0 >> 10, h0 = kc0 & 1023;
    int e = k ? s.i1 : s.i0;
    scale = k ? s.g1 : s.g0;
    src = Wo + (size_t)e * 1024 * 1024 + (size_t)h0 * 1024 + o0; // [r=hh][c=o]
    dst = WoT; dld = 2048; dr0 = o0; dc0 = kc0;
  }
  const int tid = threadIdx.x;
#pragma unroll
  for (int j = 0; j < 4; ++j) {
    int lin = j * 256 + tid;
    int r = lin >> 4, c4 = (lin & 15) * 4;
    float4 v = *(const float4*)&src[(size_t)r * 1024 + c4];
    tile[r][c4] = v.x; tile[r][c4 + 1] = v.y; tile[r][c4 + 2] = v.z; tile[r][c4 + 3] = v.w;
  }
  __syncthreads();
#pragma unroll
  for (int j = 0; j < 4; ++j) {
    int lin = j * 256 + tid;
    int r2 = lin >> 4, c2 = (lin & 15) * 4;     // r2: out row, c2: out col
    ushort4 o;
    o.x = f2bf(scale * tile[c2][r2]);
    o.y = f2bf(scale * tile[c2 + 1][r2]);
    o.z = f2bf(scale * tile[c2 + 2][r2]);
    o.w = f2bf(scale * tile[c2 + 3][r2]);
    *(ushort4*)&dst[(size_t)(dr0 + r2) * dld + dc0 + c2] = o;
  }
}

// ---------------------------------------------------------------------------
// 256x256 8-phase bf16 GEMM, barrier-diet variant: only the 3 load-bearing
// barriers per K-tile are kept -- P1-close (gates stageB vs B-reads),
// P2-close (gates stageA vs A-reads), boundary vmcnt(8)+barrier (publishes
// cross-wave global_load_lds visibility). Pacing barriers removed so
// ds_read and MFMA regions of different waves can overlap.
// ---------------------------------------------------------------------------
template <int RELU, typename OUTT>
__global__ __launch_bounds__(512) void gemm256(
    const u16* __restrict__ A, const u16* __restrict__ Bt,
    const float* __restrict__ bias, OUTT* __restrict__ C,
    int N, int K, int nN) {
  __shared__ u16 lds[65536];            // [0,32K): A dbuf | [32K,64K): B dbuf
  const int tid = threadIdx.x;
  const int wave = tid >> 6, lane = tid & 63;

  // XCD-aware bijective remap (gridDim.x % 8 == 0)
  const int cpx = gridDim.x >> 3;
  const int wg = (blockIdx.x & 7) * cpx + (blockIdx.x >> 3);
  const int m0 = (wg / nN) * 256, n0 = (wg % nN) * 256;
  const int wm = wave >> 2, wn = wave & 3;

  f32x4 acc[8][4] = {};

  const int srow = wave * 8 + (lane >> 3);
  const int gcol = (((lane & 7) ^ ((lane >> 3) & 7)) << 3);
  const u16* gA = A + (size_t)(m0 + srow) * K + gcol;
  const u16* gB = Bt + (size_t)(n0 + srow) * K + gcol;
  const int ldsOff = wave * 512;

  const int NT = K >> 6;

  auto stageA = [&](int t) {
    const u16* a = gA + t * 64;
    u16* la = lds + (t & 1) * 16384 + ldsOff;
#pragma unroll
    for (int j = 0; j < 4; ++j) async16(a + (size_t)j * 64 * K, la + j * 4096);
  };
  auto stageB = [&](int t) {
    const u16* b = gB + t * 64;
    u16* lb = lds + 32768 + (t & 1) * 16384 + ldsOff;
#pragma unroll
    for (int j = 0; j < 4; ++j) async16(b + (size_t)j * 64 * K, lb + j * 4096);
  };

  stageB(0); stageA(0);
  stageB(1); stageA(1);
  asm volatile("s_waitcnt vmcnt(8)\ns_barrier" ::: "memory");

  const int fr = lane & 15;
  const int cx = (lane & 7) << 3;
  const int cb0 = (((lane >> 4) << 3)) ^ cx;        // kk=0 col (elems)
  const int cb1 = (32 | ((lane >> 4) << 3)) ^ cx;   // kk=1 col (elems)

  bf16x8 af[4][2], b0r[2][2], b1r[2][2];

  for (int t = 0; t < NT; ++t) {
    const u16* Ab = lds + (t & 1) * 16384;
    const u16* Bb = lds + 32768 + (t & 1) * 16384;

    // ============ P0: read A[mq=0], B[nq=0]; mfma (0,0)   [no barrier]
#pragma unroll
    for (int m = 0; m < 4; ++m) {
      const int rA = (wm * 128 + m * 16 + fr) * 64;
      af[m][0] = *(const bf16x8*)(Ab + rA + cb0);
      af[m][1] = *(const bf16x8*)(Ab + rA + cb1);
    }
#pragma unroll
    for (int n = 0; n < 2; ++n) {
      const int rB = (wn * 64 + n * 16 + fr) * 64;
      b0r[n][0] = *(const bf16x8*)(Bb + rB + cb0);
      b0r[n][1] = *(const bf16x8*)(Bb + rB + cb1);
    }
    asm volatile("s_waitcnt lgkmcnt(0)" ::: "memory");
    __builtin_amdgcn_sched_barrier(0);
    __builtin_amdgcn_s_setprio(1);
#pragma unroll
    for (int m = 0; m < 4; ++m)
#pragma unroll
      for (int n = 0; n < 2; ++n) {
        MFMA_BF16(af[m][0], b0r[n][0], acc[m][n]);
        MFMA_BF16(af[m][1], b0r[n][1], acc[m][n]);
      }
    __builtin_amdgcn_s_setprio(0);

    // ============ P1: read B[nq=1]; mfma (0,1); close barrier gates stageB
#pragma unroll
    for (int n = 0; n < 2; ++n) {
      const int rB = (wn * 64 + 32 + n * 16 + fr) * 64;
      b1r[n][0] = *(const bf16x8*)(Bb + rB + cb0);
      b1r[n][1] = *(const bf16x8*)(Bb + rB + cb1);
    }
    asm volatile("s_waitcnt lgkmcnt(0)" ::: "memory");
    __builtin_amdgcn_sched_barrier(0);
    __builtin_amdgcn_s_setprio(1);
#pragma unroll
    for (int m = 0; m < 4; ++m)
#pragma unroll
      for (int n = 0; n < 2; ++n) {
        MFMA_BF16(af[m][0], b1r[n][0], acc[m][2 + n]);
        MFMA_BF16(af[m][1], b1r[n][1], acc[m][2 + n]);
      }
    __builtin_amdgcn_s_setprio(0);
    __builtin_amdgcn_s_barrier();       // all B-reads of buf(t&1) drained

    // ============ P2: read A[mq=1]; stage B(t+2); mfma (1,1); close barrier
#pragma unroll
    for (int m = 0; m < 4; ++m) {
      const int rA = (wm * 128 + 64 + m * 16 + fr) * 64;
      af[m][0] = *(const bf16x8*)(Ab + rA + cb0);
      af[m][1] = *(const bf16x8*)(Ab + rA + cb1);
    }
    if (t + 2 < NT) stageB(t + 2);
    asm volatile("s_waitcnt lgkmcnt(0)" ::: "memory");
    __builtin_amdgcn_sched_barrier(0);
    __builtin_amdgcn_s_setprio(1);
#pragma unroll
    for (int m = 0; m < 4; ++m)
#pragma unroll
      for (int n = 0; n < 2; ++n) {
        MFMA_BF16(af[m][0], b1r[n][0], acc[4 + m][2 + n]);
        MFMA_BF16(af[m][1], b1r[n][1], acc[4 + m][2 + n]);
      }
    __builtin_amdgcn_s_setprio(0);
    __builtin_amdgcn_s_barrier();       // all A-reads of buf(t&1) drained

    // ============ P3: stage A(t+2); mfma (1,0); boundary wait
    if (t + 2 < NT) stageA(t + 2);
    __builtin_amdgcn_s_setprio(1);
#pragma unroll
    for (int m = 0; m < 4; ++m)
#pragma unroll
      for (int n = 0; n < 2; ++n) {
        MFMA_BF16(af[m][0], b0r[n][0], acc[4 + m][n]);
        MFMA_BF16(af[m][1], b0r[n][1], acc[4 + m][n]);
      }
    __builtin_amdgcn_s_setprio(0);
    if (t + 2 < NT)
      asm volatile("s_waitcnt vmcnt(8)\ns_barrier" ::: "memory");
    else if (t + 1 < NT)
      asm volatile("s_waitcnt vmcnt(0)\ns_barrier" ::: "memory");
  }

  if constexpr (sizeof(OUTT) == 2) {
    // ---- bf16: LDS-transpose epilogue. Swizzle: granule ^= (row>>2)&7.
    __syncthreads();                     // staging LDS now dead
#pragma unroll
    for (int nf = 0; nf < 4; ++nf) {
      const int col = wn * 64 + nf * 16 + fr;
      const float bv = bias[n0 + col];
#pragma unroll
      for (int mf = 0; mf < 8; ++mf) {
#pragma unroll
        for (int r = 0; r < 4; ++r) {
          const int row = wm * 128 + mf * 16 + (lane >> 4) * 4 + r;
          float v = acc[mf][nf][r] + bv;
          if (RELU) v = fmaxf(v, 0.f);
          lds[row * 256 + ((((col >> 3) ^ ((row >> 2) & 7)) << 3) | (col & 7))] =
              f2bf(v);
        }
      }
    }
    __syncthreads();
#pragma unroll
    for (int i = 0; i < 16; ++i) {
      const int ou = i * 4096 + tid * 8;          // u16 units
      const int row = ou >> 8;
      const int gp = (ou >> 3) & 31;
      const int cl = ((gp ^ ((row >> 2) & 7)) << 3);
      bf16x8 v = *(const bf16x8*)(lds + row * 256 + gp * 8);
      *(bf16x8*)&C[(size_t)(m0 + row) * N + n0 + cl] = v;
    }
  } else {
    // ---- f32: direct store path (64 B runs = full sectors)
#pragma unroll
    for (int nf = 0; nf < 4; ++nf) {
      const int col = n0 + wn * 64 + nf * 16 + fr;
      const float bv = bias[col];
#pragma unroll
      for (int mf = 0; mf < 8; ++mf) {
#pragma unroll
        for (int r = 0; r < 4; ++r) {
          const int row = m0 + wm * 128 + mf * 16 + (lane >> 4) * 4 + r;
          float v = acc[mf][nf][r] + bv;
          if (RELU) v = fmaxf(v, 0.f);
          C[(size_t)row * N + col] = v;
        }
      }
    }
  }
}

// ---------------------------------------------------------------------------
extern "C" void kernel_launch(void* const* d_in, const int* in_sizes, int n_in,
                              void* d_out, int out_size, void* d_ws, size_t ws_size,
                              hipStream_t stream) {
  const float* x     = (const float*)d_in[0];
  const float* noise = (const float*)d_in[1];
  const float* gw    = (const float*)d_in[2];
  const float* gn    = (const float*)d_in[3];
  const float* Wi    = (const float*)d_in[4];
  const float* bi    = (const float*)d_in[5];
  const float* Wo    = (const float*)d_in[6];
  const float* bo    = (const float*)d_in[7];
  float* out = (float*)d_out;

  char* w = (char*)d_ws;
  float* part    = (float*)(w + 0x000000);       // 512 KB: [1024][128]
  float* p2      = (float*)(w + 0x080000);       //  16 KB: [32][128]
  Sel*   sel     = (Sel*)  (w + 0x084000);       //  16 B
  float* bi_comb = (float*)(w + 0x084100);       //   8 KB
  float* bo_comb = (float*)(w + 0x086100);       //   4 KB
  u16*   gbT     = (u16*)  (w + 0x090000);       // 256 KB: [128][1024] (pre-swizzled)
  u16*   xb      = (u16*)  (w + 0x0200000);      //  32 MB: [16384][1024]
  u16*   WiT     = (u16*)  (w + 0x2200000);      //   4 MB: [2048][1024]
  u16*   WoT     = (u16*)  (w + 0x2600000);      //   4 MB: [1024][2048]
  u16*   h       = (u16*)  (w + 0x2A00000);      //  64 MB: [16384][2048]

  cvt_gb<<<16, 256, 0, stream>>>(gw, gn, gbT);
  gate_fused<<<1024, 256, 0, stream>>>(x, gbT, xb, part);
  reduce_parts<<<32, 256, 0, stream>>>(part, p2);
  select_kernel<<<1, 256, 0, stream>>>(p2, noise, bi, bo, sel, bi_comb, bo_comb);
  prep_weights<<<1024, 256, 0, stream>>>(Wi, Wo, sel, WiT, WoT);
  // GEMM1: [16384,1024] x [1024,2048] -> h ; grid 64x8 = 512
  gemm256<1, u16>  <<<512, 512, 0, stream>>>(xb, WiT, bi_comb, h, 2048, 1024, 8);
  // GEMM2: [16384,2048] x [2048,1024] -> out ; grid 64x4 = 256
  gemm256<0, float><<<256, 512, 0, stream>>>(h, WoT, bo_comb, out, 1024, 2048, 4);
}